// Round 5
// baseline (172.728 us; speedup 1.0000x reference)
//
#include <hip/hip_runtime.h>

// Problem constants (from reference)
#define VOCAB 50000
#define DIM   50
#define B_TOT 131072
#define CTX   10
#define NEG   10
#define EPS_F 1e-10f
#define PAIRS (B_TOT / 2)

constexpr int TPB    = 256;   // 4 waves
constexpr int BLOCKS = 2048;  // 8192 waves; 8 pair-iterations per wave

// Half-wave (32 lanes) per sample; lane l holds float2 slot p = min(l,24).
//
// R5 vs R4: R4 kept VGPR_Count=40 -> sched_barrier(0) failed to hold the 21
// gather results live; effective MLP ~1 per wave (Little's law from 7 TB/s
// L1-fill). Fixes:
//  1. asm volatile("" ::: "memory") AFTER the 21 gathers: an IR-level memory
//     clobber. Loads cannot sink past it; consumers depend on the results ->
//     all 42 result VGPRs live at the barrier -> true 21-deep vmem burst.
//  2. All 21 index broadcasts materialized into registers BEFORE the gather
//     burst, so DS waits don't interleave with load issue.
// This round doubles as the experiment separating "MLP-bound" (dur drops to
// 40-60us) from "L3 random-line BW-bound" (VGPR jumps but dur stays ~100us).
__global__ __launch_bounds__(TPB, 4) void cbow_loss(
    const int*   __restrict__ ctx_idx,   // [B, CTX]
    const int*   __restrict__ pos_idx,   // [B]
    const int*   __restrict__ neg_idx,   // [B, NEG]
    const float* __restrict__ inW,       // [VOCAB, DIM]
    const float* __restrict__ outW,      // [VOCAB, DIM]
    float*       __restrict__ partials)  // [BLOCKS]
{
    const int lane = threadIdx.x & 63;
    const int sub  = lane >> 5;          // which half-wave -> which sample
    const int l    = lane & 31;          // lane within half-wave
    const int p    = (l < 25) ? l : 24;  // clamped float2 slot
    const bool act = (l < 25);

    const int wave_in_block = threadIdx.x >> 6;          // 0..3
    const int gwave  = blockIdx.x * (TPB / 64) + wave_in_block;
    const int nwaves = BLOCKS * (TPB / 64);

    const float2* __restrict__ inW2  = (const float2*)inW;   // row stride 25
    const float2* __restrict__ outW2 = (const float2*)outW;

    // per-lane index slot: l in 0..9 -> ctx[l]; l==10 -> pos; 11..20 -> neg[l-11]
    auto idx_addr = [&](int b) -> const int* {
        if (l < CTX)      return ctx_idx + b * CTX + l;
        if (l == CTX)     return pos_idx + b;
        if (l < CTX + 1 + NEG) return neg_idx + b * NEG + (l - CTX - 1);
        return pos_idx + b;  // lanes 21..31: harmless in-bounds dummy
    };

    float loss_lane = 0.f;   // per-lane packed loss accumulator

    int pair = gwave;
    int my_idx = *idx_addr(2 * pair + sub);   // prologue: first pair's indices

    while (pair < PAIRS) {
        // ---- broadcast ALL 21 indices into registers first (DS pipe) ----
        int idxs[CTX + 1 + NEG];
        #pragma unroll
        for (int s = 0; s < CTX + 1 + NEG; ++s)
            idxs[s] = __shfl(my_idx, (lane & 32) + s);

        // ---- issue ALL 21 row-gathers back-to-back ----
        float2 cv_[CTX], nv[NEG], pv;
        #pragma unroll
        for (int s = 0; s < CTX; ++s) cv_[s] = inW2[idxs[s] * 25 + p];
        pv = outW2[idxs[CTX] * 25 + p];
        #pragma unroll
        for (int k = 0; k < NEG; ++k) nv[k] = outW2[idxs[CTX + 1 + k] * 25 + p];

        // ---- prefetch next pair's indices (1 vmem) while gathers fly ----
        const int npair = pair + nwaves;
        const int nb = 2 * ((npair < PAIRS) ? npair : pair) + sub;
        const int next_idx = *idx_addr(nb);

        // ---- memory clobber: no load sinks below, forcing 21-deep burst ----
        asm volatile("" ::: "memory");

        // ---- context mean ----
        float cvx = 0.f, cvy = 0.f;
        #pragma unroll
        for (int j = 0; j < CTX; ++j) { cvx += cv_[j].x; cvy += cv_[j].y; }
        cvx *= (1.f / CTX);
        cvy *= (1.f / CTX);

        // ---- 11 scores, packed one per lane ----
        float packed = 0.f;
        {
            float prod = act ? (cvx * pv.x + cvy * pv.y) : 0.f;
            prod += __shfl_xor(prod, 1);
            prod += __shfl_xor(prod, 2);
            prod += __shfl_xor(prod, 4);
            prod += __shfl_xor(prod, 8);
            prod += __shfl_xor(prod, 16);
            packed = (l == 0) ? prod : packed;     // lane 0: pos score
        }
        #pragma unroll
        for (int k = 0; k < NEG; ++k) {
            float prod = act ? (cvx * nv[k].x + cvy * nv[k].y) : 0.f;
            prod += __shfl_xor(prod, 1);
            prod += __shfl_xor(prod, 2);
            prod += __shfl_xor(prod, 4);
            prod += __shfl_xor(prod, 8);
            prod += __shfl_xor(prod, 16);
            packed = (l == k + 1) ? prod : packed; // lane k+1: neg score k
        }

        // ---- loss math once for all 11 scores (lanes 0..10) ----
        const float z   = (l == 0) ? packed : -packed;
        const float sig = 1.f / (1.f + __expf(-z));
        const float c   = __logf(sig + EPS_F);
        loss_lane += (l < NEG + 1) ? c : 0.f;

        my_idx = next_idx;
        pair   = npair;
    }

    // ---- single cross-lane reduce at the end ----
    loss_lane += __shfl_xor(loss_lane, 1);
    loss_lane += __shfl_xor(loss_lane, 2);
    loss_lane += __shfl_xor(loss_lane, 4);
    loss_lane += __shfl_xor(loss_lane, 8);
    loss_lane += __shfl_xor(loss_lane, 16);
    loss_lane += __shfl_xor(loss_lane, 32);

    __shared__ float s_part[TPB / 64];
    if (lane == 0) s_part[wave_in_block] = loss_lane;
    __syncthreads();
    if (threadIdx.x == 0) {
        float s = 0.f;
        #pragma unroll
        for (int w = 0; w < TPB / 64; ++w) s += s_part[w];
        partials[blockIdx.x] = s;
    }
}

__global__ __launch_bounds__(256) void cbow_finalize(
    const float* __restrict__ partials, float* __restrict__ out)
{
    float s = 0.f;
    for (int i = threadIdx.x; i < BLOCKS; i += 256) s += partials[i];
    #pragma unroll
    for (int k = 32; k >= 1; k >>= 1) s += __shfl_xor(s, k);  // 64-lane reduce
    __shared__ float sm[4];
    const int w = threadIdx.x >> 6;
    if ((threadIdx.x & 63) == 0) sm[w] = s;
    __syncthreads();
    if (threadIdx.x == 0)
        out[0] = -(sm[0] + sm[1] + sm[2] + sm[3]) * (1.f / (float)B_TOT);
}

extern "C" void kernel_launch(void* const* d_in, const int* in_sizes, int n_in,
                              void* d_out, int out_size, void* d_ws, size_t ws_size,
                              hipStream_t stream) {
    const int*   ctx_idx = (const int*)  d_in[0];  // [B, CTX]
    const int*   pos_idx = (const int*)  d_in[1];  // [B]
    const int*   neg_idx = (const int*)  d_in[2];  // [B, NEG]
    const float* inW     = (const float*)d_in[3];  // [VOCAB, DIM]
    const float* outW    = (const float*)d_in[4];  // [VOCAB, DIM]
    float*       out      = (float*)d_out;
    float*       partials = (float*)d_ws;          // BLOCKS floats

    cbow_loss<<<BLOCKS, TPB, 0, stream>>>(ctx_idx, pos_idx, neg_idx, inW, outW, partials);
    cbow_finalize<<<1, 256, 0, stream>>>(partials, out);
}